// Round 2
// baseline (558.520 us; speedup 1.0000x reference)
//
#include <hip/hip_runtime.h>
#include <cstdint>

typedef __bf16 bf16x8 __attribute__((ext_vector_type(8)));
typedef float floatx4 __attribute__((ext_vector_type(4)));
typedef unsigned short u16;
typedef unsigned int u32;

#define ATTN_SCALE 0.08838834764831845f  // 1/sqrt(128)

__device__ __forceinline__ u16 f2bf(float f) {
  union { float f; u32 i; } v; v.f = f;
  u32 r = v.i + 0x7fffu + ((v.i >> 16) & 1u);
  return (u16)(r >> 16);
}

// ---------------- fp32 -> bf16 elementwise convert ---------------------------
__global__ __launch_bounds__(256) void convert_bf16(
    const float* __restrict__ src, u16* __restrict__ dst, int n4) {
  int i = blockIdx.x * 256 + threadIdx.x;
  if (i >= n4) return;
  float4 v = ((const float4*)src)[i];
  ushort4 o;
  o.x = f2bf(v.x); o.y = f2bf(v.y); o.z = f2bf(v.z); o.w = f2bf(v.w);
  ((ushort4*)dst)[i] = o;
}

// ---------------- transpose (fp32 in, bf16 out), up-to-3 concat sources ------
// Builds Bt[n][k] (row stride K, bf16) from fp32 W0[K][ld0]|W1[K][ld1]|W2[K][ld2]
// columns [0,n1) from W0, [n1,n2) from W1, [n2,N) from W2. 32x32 tiles.
__global__ __launch_bounds__(256) void transpose_cat(
    const float* __restrict__ W0, const float* __restrict__ W1,
    const float* __restrict__ W2,
    int n1, int n2, int ld0, int ld1, int ld2, int K, u16* __restrict__ Bt) {
  __shared__ u16 tile[32][33];
  const int k0 = blockIdx.x * 32, n0 = blockIdx.y * 32;
  const float* src; int ld, nb;
  if (n0 < n1)      { src = W0; ld = ld0; nb = n0; }
  else if (n0 < n2) { src = W1; ld = ld1; nb = n0 - n1; }
  else              { src = W2; ld = ld2; nb = n0 - n2; }
  const int tx = threadIdx.x, ty = threadIdx.y;
#pragma unroll
  for (int i = 0; i < 4; i++) {
    int k = ty + i * 8;
    tile[k][tx] = f2bf(src[(size_t)(k0 + k) * ld + nb + tx]);
  }
  __syncthreads();
#pragma unroll
  for (int i = 0; i < 4; i++) {
    int n = ty + i * 8;
    Bt[(size_t)(n0 + n) * K + k0 + tx] = tile[tx][n];
  }
}

// ---------------- GEMM: C[M,N] = A[M,K] @ Bt[N,K]^T (+bias) ------------------
// A, Bt are bf16 bits; bias fp32. 128x128 tile, BK=32, 256 threads (4 waves,
// 2x2 of 64x64), 16x16x32 bf16 MFMA.
// EPI 0: QKV scatter epilogue (Q natural bf16, K natural bf16, V transposed bf16).
// EPI 1: fp32 output with bias.
template <int EPI>
__global__ __launch_bounds__(256) void gemm_bt(
    const u16* __restrict__ A, const u16* __restrict__ Bt,
    const float* __restrict__ bias0, const float* __restrict__ bias1,
    const float* __restrict__ bias2,
    u16* __restrict__ out0, u16* __restrict__ out1, u16* __restrict__ out2,
    float* __restrict__ outf,
    int M, int N, int K) {
  // stride 40 u16 = 80B: 16B-aligned rows, 2-way LDS bank conflicts only
  __shared__ u16 As[128][40];
  __shared__ u16 Bs[128][40];
  const int tid  = threadIdx.x;
  const int w    = tid >> 6, L = tid & 63, ln = L & 15, quad = L >> 4;
  const int m0   = blockIdx.y * 128, n0 = blockIdx.x * 128;
  const int mw   = (w & 1) * 64, nw = (w >> 1) * 64;
  const int ar   = tid >> 2, ac = tid & 3;  // staging: 64 rows/pass, 4x16B chunks/row
  floatx4 acc[4][4] = {};

  for (int kt = 0; kt < K; kt += 32) {
    __syncthreads();
#pragma unroll
    for (int p = 0; p < 2; p++) {
      uint4 va = *(const uint4*)&A[(size_t)(m0 + p * 64 + ar) * K + kt + ac * 8];
      *(uint4*)&As[p * 64 + ar][ac * 8] = va;
      uint4 vb = *(const uint4*)&Bt[(size_t)(n0 + p * 64 + ar) * K + kt + ac * 8];
      *(uint4*)&Bs[p * 64 + ar][ac * 8] = vb;
    }
    __syncthreads();
    bf16x8 af[4], bf[4];
#pragma unroll
    for (int mb = 0; mb < 4; mb++) af[mb] = *(const bf16x8*)&As[mw + mb * 16 + ln][quad * 8];
#pragma unroll
    for (int nb = 0; nb < 4; nb++) bf[nb] = *(const bf16x8*)&Bs[nw + nb * 16 + ln][quad * 8];
#pragma unroll
    for (int mb = 0; mb < 4; mb++)
#pragma unroll
      for (int nb = 0; nb < 4; nb++)
        acc[mb][nb] = __builtin_amdgcn_mfma_f32_16x16x32_bf16(af[mb], bf[nb], acc[mb][nb], 0, 0, 0);
  }

#pragma unroll
  for (int mb = 0; mb < 4; mb++) {
#pragma unroll
    for (int nb = 0; nb < 4; nb++) {
#pragma unroll
      for (int r = 0; r < 4; r++) {
        const int m = m0 + mw + mb * 16 + quad * 4 + r;
        const int n = n0 + nw + nb * 16 + ln;
        float v = acc[mb][nb][r];
        if constexpr (EPI == 0) {
          if (n < 2048) {            // Q: bf16 [4096][2048]
            v += bias0[n];
            out0[(size_t)m * 2048 + n] = f2bf(v);
          } else if (n < 2304) {     // K: bf16 [4096][256]
            const int j = n - 2048;
            v += bias1[j];
            out1[(size_t)m * 256 + j] = f2bf(v);
          } else {                   // V transposed: Vt[(b*2+hk)*128+d][t]
            const int j = n - 2304;  // j = hk*128 + d
            v += bias2[j];
            const int b = m >> 11, t = m & 2047;
            out2[((size_t)(b * 256 + j)) * 2048 + t] = f2bf(v);
          }
        } else {
          v += bias0[n];
          outf[(size_t)m * (size_t)N + n] = v;
        }
      }
    }
  }
}

// ---------------- flash attention -------------------------------------------
// Grid (T/64, H, B); 256 threads = 4 waves; wave w owns query rows [w*16, w*16+16).
// Q[4096][2048], K[4096][256], Vt[(b*2+hk)*128+d][2048], O[4096][2048] (all bf16 bits)
__global__ __launch_bounds__(256) void attn_kernel(
    const u16* __restrict__ Q, const u16* __restrict__ K,
    const u16* __restrict__ Vt, u16* __restrict__ O) {
  __shared__ u16 Ks[64][136];     // keys x d, stride 136 (16B-aligned, 2-way banks)
  __shared__ u16 Vs[128][72];     // d x keys
  __shared__ u16 Ps[4][16][72];   // per-wave P round-trip (C-layout -> A-layout)
  const int tid = threadIdx.x;
  const int w = tid >> 6, L = tid & 63, ln = L & 15, quad = L >> 4;
  const int qt = blockIdx.x, h = blockIdx.y, b = blockIdx.z;
  const int hk = h >> 3;  // G = 8
  const size_t qrow0 = (size_t)b * 2048 + qt * 64 + w * 16;

  bf16x8 qf[4];
#pragma unroll
  for (int kc = 0; kc < 4; kc++)
    qf[kc] = *(const bf16x8*)&Q[(qrow0 + ln) * 2048 + h * 128 + kc * 32 + quad * 8];

  floatx4 o[8] = {};
  float mrow[4] = {-1e30f, -1e30f, -1e30f, -1e30f};
  float lrow[4] = {0.f, 0.f, 0.f, 0.f};
  const u16* Kbase = K + (size_t)b * 2048 * 256 + hk * 128;
  const u16* Vbase = Vt + (size_t)(b * 2 + hk) * 128 * 2048;

  for (int s0 = 0; s0 < 2048; s0 += 64) {
    __syncthreads();
#pragma unroll
    for (int it = 0; it < 4; it++) {  // K tile: 64 rows x 256B
      int r = (tid >> 4) + it * 16, c = tid & 15;
      *(uint4*)&Ks[r][c * 8] = *(const uint4*)&Kbase[(size_t)(s0 + r) * 256 + c * 8];
    }
#pragma unroll
    for (int it = 0; it < 4; it++) {  // V tile: 128 rows(d) x 128B(s)
      int d = (tid >> 3) + it * 32, c = tid & 7;
      *(uint4*)&Vs[d][c * 8] = *(const uint4*)&Vbase[(size_t)d * 2048 + s0 + c * 8];
    }
    __syncthreads();

    floatx4 sf[4] = {};
#pragma unroll
    for (int kc = 0; kc < 4; kc++) {
#pragma unroll
      for (int nb = 0; nb < 4; nb++) {
        bf16x8 kf = *(const bf16x8*)&Ks[nb * 16 + ln][kc * 32 + quad * 8];
        sf[nb] = __builtin_amdgcn_mfma_f32_16x16x32_bf16(qf[kc], kf, sf[nb], 0, 0, 0);
      }
    }
#pragma unroll
    for (int nb = 0; nb < 4; nb++)
#pragma unroll
      for (int r = 0; r < 4; r++) {
        float v = sf[nb][r] * ATTN_SCALE;
        sf[nb][r] = fminf(fmaxf(v, -100.f), 100.f);
      }

    float alpha[4];
#pragma unroll
    for (int r = 0; r < 4; r++) {
      float mx = fmaxf(fmaxf(sf[0][r], sf[1][r]), fmaxf(sf[2][r], sf[3][r]));
#pragma unroll
      for (int off = 1; off < 16; off <<= 1) mx = fmaxf(mx, __shfl_xor(mx, off));
      float mn = fmaxf(mrow[r], mx);
      alpha[r] = __expf(mrow[r] - mn);
      mrow[r] = mn;
      float s = 0.f;
#pragma unroll
      for (int nb = 0; nb < 4; nb++) {
        float p = __expf(sf[nb][r] - mn);
        sf[nb][r] = p;
        s += p;
      }
#pragma unroll
      for (int off = 1; off < 16; off <<= 1) s += __shfl_xor(s, off);
      lrow[r] = lrow[r] * alpha[r] + s;
    }
#pragma unroll
    for (int nb = 0; nb < 8; nb++)
#pragma unroll
      for (int r = 0; r < 4; r++) o[nb][r] *= alpha[r];

    // P (C-layout in regs) -> per-wave LDS -> A-layout frags
#pragma unroll
    for (int nb = 0; nb < 4; nb++)
#pragma unroll
      for (int r = 0; r < 4; r++)
        Ps[w][quad * 4 + r][nb * 16 + ln] = f2bf(sf[nb][r]);
#pragma unroll
    for (int kc = 0; kc < 2; kc++) {
      bf16x8 pf = *(const bf16x8*)&Ps[w][ln][kc * 32 + quad * 8];
#pragma unroll
      for (int nb = 0; nb < 8; nb++) {
        bf16x8 vf = *(const bf16x8*)&Vs[nb * 16 + ln][kc * 32 + quad * 8];
        o[nb] = __builtin_amdgcn_mfma_f32_16x16x32_bf16(pf, vf, o[nb], 0, 0, 0);
      }
    }
  }

#pragma unroll
  for (int r = 0; r < 4; r++) {
    float inv = 1.f / lrow[r];
    size_t row = qrow0 + quad * 4 + r;
#pragma unroll
    for (int nb = 0; nb < 8; nb++)
      O[row * 2048 + h * 128 + nb * 16 + ln] = f2bf(o[nb][r] * inv);
  }
}

extern "C" void kernel_launch(void* const* d_in, const int* in_sizes, int n_in,
                              void* d_out, int out_size, void* d_ws, size_t ws_size,
                              hipStream_t stream) {
  const float* x  = (const float*)d_in[0];
  const float* Wq = (const float*)d_in[1];
  const float* bq = (const float*)d_in[2];
  const float* Wk = (const float*)d_in[3];
  const float* bk = (const float*)d_in[4];
  const float* Wv = (const float*)d_in[5];
  const float* bv = (const float*)d_in[6];
  const float* Wo = (const float*)d_in[7];
  const float* bo = (const float*)d_in[8];
  float* out = (float*)d_out;

  // Workspace layout (bytes). xb is dead after the QKV GEMM, so Ob aliases it.
  char* ws = (char*)d_ws;
  u16* xb     = (u16*)(ws);                      // 4096*2048*2 = 16777216
  u16* Ob     = (u16*)(ws);                      // aliases xb (attn runs after gemm1)
  u16* Wqkv_t = (u16*)(ws + 16777216);           // 2560*2048*2 = 10485760
  u16* Wot    = (u16*)(ws + 27262976);           // 2048*2048*2 =  8388608
  u16* Qb     = (u16*)(ws + 35651584);           // 4096*2048*2 = 16777216
  u16* Kb     = (u16*)(ws + 52428800);           // 4096*256*2  =  2097152
  u16* Vtb    = (u16*)(ws + 54525952);           // 512*2048*2  =  2097152
  (void)in_sizes; (void)n_in; (void)out_size; (void)ws_size;

  // x (fp32) -> bf16
  convert_bf16<<<8192, 256, 0, stream>>>(x, xb, 2097152);

  // Wqkv_t[n][k]: cols [0,2048)=Wq, [2048,2304)=Wk, [2304,2560)=Wv (fp32 -> bf16)
  transpose_cat<<<dim3(64, 80), dim3(32, 8), 0, stream>>>(
      Wq, Wk, Wv, 2048, 2304, 2048, 256, 256, 2048, Wqkv_t);
  transpose_cat<<<dim3(64, 64), dim3(32, 8), 0, stream>>>(
      Wo, Wo, Wo, 2048, 2048, 2048, 2048, 2048, 2048, Wot);

  gemm_bt<0><<<dim3(20, 32), 256, 0, stream>>>(
      xb, Wqkv_t, bq, bk, bv, Qb, Kb, Vtb, nullptr, 4096, 2560, 2048);

  attn_kernel<<<dim3(32, 16, 2), 256, 0, stream>>>(Qb, Kb, Vtb, Ob);

  gemm_bt<1><<<dim3(16, 32), 256, 0, stream>>>(
      Ob, Wot, bo, nullptr, nullptr, nullptr, nullptr, nullptr, out, 4096, 2048, 2048);
}